// Round 15
// baseline (7521.362 us; speedup 1.0000x reference)
//
#include <hip/hip_runtime.h>
#include <hip/hip_bf16.h>
#include <hip/hip_fp16.h>

#define TT 2048
#define BB 64
#define HH 512
#define GG 2048  // 4H

typedef __attribute__((ext_vector_type(4))) float f32x4;
typedef __attribute__((ext_vector_type(8))) short short8;
typedef __attribute__((ext_vector_type(4))) short short4v;
typedef __attribute__((ext_vector_type(4))) unsigned u32x4;
typedef unsigned long long ull;

static __device__ __forceinline__ short f2bf(float f) {
  unsigned u = __builtin_bit_cast(unsigned, f);
  u = (u + 0x7FFFu + ((u >> 16) & 1u)) >> 16;
  return (short)u;
}
static __device__ __forceinline__ float fsigmoid(float x) { return 1.0f / (1.0f + __expf(-x)); }
static __device__ __forceinline__ float ftanh(float x) {
  float e = __expf(2.0f * x);
  return 1.0f - 2.0f / (e + 1.0f);
}
static __device__ __forceinline__ float h2f(unsigned short u) {
  __half h = __builtin_bit_cast(__half, u);
  return __half2float(h);
}

// ---------------- fp32 -> bf16 convert ----------------
__global__ void cvt_bf16_kernel(const float4* __restrict__ in, short4v* __restrict__ outp, long n4) {
  long i = (long)blockIdx.x * blockDim.x + threadIdx.x;
  long stride = (long)gridDim.x * blockDim.x;
  for (; i < n4; i += stride) {
    float4 v = in[i];
    short4v o;
    o[0] = f2bf(v.x); o[1] = f2bf(v.y); o[2] = f2bf(v.z); o[3] = f2bf(v.w);
    outp[i] = o;
  }
}

// ---------------- sync init at the coherence point: [0..63] flags, [64..1087] ready ----
__global__ void init_sync(unsigned* base) {
  int i = blockIdx.x * 256 + threadIdx.x;
  if (i < 1088)
    __hip_atomic_store(base + i, 0u, __ATOMIC_RELAXED, __HIP_MEMORY_SCOPE_AGENT);
}

// ================= mega-kernel =================
// xpart gate-planar dwords (r10-proven): idx = (((t*4 + q)*4 + bg)*8 + cp)*512 + thr
//   dword = [cellA gate-q f16 | cellB gate-q f16], thr = w*64 + g4*16 + b16 (scan tid)
// ready[mt] counts n-tile blocks (16 each) whose stores for m-tile mt are at the MALL.

// ---- GEMM side: r10's 256-thread gemm_xpart transplanted; threads 256-511 only barrier ----
__device__ __forceinline__ void gemm_part(
    char* smem, int vb,
    const __hip_bfloat16* __restrict__ Abf, const __hip_bfloat16* __restrict__ Bbf,
    const float* __restrict__ bih, const float* __restrict__ bhh,
    char* xpart, unsigned* ready) {
  __hip_bfloat16* As = (__hip_bfloat16*)smem;
  __hip_bfloat16* Bs = As + 8192;
  const int mt = vb >> 4;  // ascending with blockIdx -> tiles complete roughly in t-order
  const int nt = vb & 15;
  const size_t m0 = (size_t)mt * 128;
  const int n0 = nt * 128;
  const int tid = threadIdx.x;
  const int lane = tid & 63;
  const int w = tid >> 6;  // compute uses w 0..3 only
  const int wm = w >> 1, wn = w & 1;
  const int g = lane >> 4;
  const int l15 = lane & 15;
  f32x4 acc[4][4] = {};
  for (int k0 = 0; k0 < 512; k0 += 64) {
    if (tid < 256) {
#pragma unroll
      for (int i = 0; i < 4; i++) {
        const int slot = w * 4 + i;
        const int row = slot * 8 + (lane >> 3);
        const int segS = (lane & 7) ^ (row & 7);
        const __hip_bfloat16* ga = Abf + (m0 + row) * 512 + k0 + segS * 8;
        const __hip_bfloat16* gb = Bbf + (size_t)(n0 + row) * 512 + k0 + segS * 8;
        __builtin_amdgcn_global_load_lds(
            (const __attribute__((address_space(1))) unsigned*)(const void*)ga,
            (__attribute__((address_space(3))) unsigned*)(void*)(As + slot * 512), 16, 0, 0);
        __builtin_amdgcn_global_load_lds(
            (const __attribute__((address_space(1))) unsigned*)(const void*)gb,
            (__attribute__((address_space(3))) unsigned*)(void*)(Bs + slot * 512), 16, 0, 0);
      }
    }
    __syncthreads();
    if (tid < 256) {
#pragma unroll
      for (int kk = 0; kk < 2; kk++) {
        short8 av[4], bv[4];
#pragma unroll
        for (int f = 0; f < 4; f++) {
          const int row = wm * 64 + f * 16 + l15;
          av[f] = *(const short8*)(As + row * 64 + ((((kk << 2) + g) ^ (row & 7)) << 3));
        }
#pragma unroll
        for (int f = 0; f < 4; f++) {
          const int row = wn * 64 + f * 16 + l15;
          bv[f] = *(const short8*)(Bs + row * 64 + ((((kk << 2) + g) ^ (row & 7)) << 3));
        }
#pragma unroll
        for (int fi = 0; fi < 4; fi++)
#pragma unroll
          for (int fj = 0; fj < 4; fj++)
            acc[fi][fj] = __builtin_amdgcn_mfma_f32_16x16x32_bf16(av[fi], bv[fj], acc[fi][fj], 0, 0, 0);
      }
    }
    __syncthreads();
  }
  // epilogue: r10 address math; fj and fj+2 share one dword (slot 0/1) -> packed sc0sc1 store
  if (tid < 256) {
    const int q = nt >> 2;
    const int gt = mt * 2 + wm;
    const int cp = (nt & 3) * 2 + wn;
    const int g4s = l15 & 3;
#pragma unroll
    for (int fjp = 0; fjp < 2; fjp++) {
      const int nlo = n0 + wn * 64 + fjp * 16 + l15;
      const int nhi = nlo + 32;
      const float bLo = bih[nlo] + bhh[nlo];
      const float bHi = bih[nhi] + bhh[nhi];
      const int wpart = fjp * 4 + (l15 >> 2);
#pragma unroll
      for (int fi = 0; fi < 4; fi++) {
#pragma unroll
        for (int r = 0; r < 4; r++) {
          const int thr = wpart * 64 + g4s * 16 + (g * 4 + r);
          __half lo = __float2half(acc[fi][fjp][r] + bLo);
          __half hi = __float2half(acc[fi][fjp + 2][r] + bHi);
          unsigned d = (unsigned)__builtin_bit_cast(unsigned short, lo) |
                       ((unsigned)__builtin_bit_cast(unsigned short, hi) << 16);
          const ull dwi = ((((ull)gt * 4 + q) * 4 + fi) * 8 + cp) * 512 + (ull)thr;
          const ull ga = (ull)(uintptr_t)xpart + dwi * 4ull;
          asm volatile("global_store_dword %0, %1, off sc0 sc1" ::"v"(ga), "v"(d));
        }
      }
    }
    asm volatile("s_waitcnt vmcnt(0)" ::: "memory");
  }
  __syncthreads();
  if (tid == 0)
    __hip_atomic_fetch_add(ready + mt, 1u, __ATOMIC_RELAXED, __HIP_MEMORY_SCOPE_AGENT);
}

// ---- scan side: r10's lstm_scan_kernel verbatim + ready gates ----
__device__ __forceinline__ void scan_part(
    char* smem, const char* xpart, const float* __restrict__ Whh,
    char* hbuf, float* __restrict__ outp, unsigned* flags, unsigned* ready) {
  char* Hs = smem;  // 16KB: [b(16)][seg(64) x 16B], seg stored at (seg ^ (b&7))
  const int blk = blockIdx.x;
  const int bg = blk >> 3;
  const int cp = blk & 7;
  const int tid = threadIdx.x;
  const int lane = tid & 63;
  const int w = tid >> 6;  // 0..7
  const int b16 = lane & 15;
  const int g4 = lane >> 4;
  const int qr = b16 & 3;
  const int jj = b16 >> 2;
  const int colA = cp * 64 + w * 4 + g4;
  const int colB = cp * 64 + (w + 8) * 4 + g4;
  const int batchg = bg * 16 + b16;

  // one-time: W_hh slices -> registers (bf16 A-frags)
  const int rowA = qr * 512 + cp * 64 + w * 4 + jj;
  const int rowB = qr * 512 + cp * 64 + (w + 8) * 4 + jj;
  short8 wA[16], wB[16];
#pragma unroll
  for (int kt = 0; kt < 16; kt++) {
    const float* pa = Whh + (size_t)rowA * 512 + kt * 32 + g4 * 8;
    const float* pb = Whh + (size_t)rowB * 512 + kt * 32 + g4 * 8;
    float4 a0 = *(const float4*)pa;
    float4 a1 = *(const float4*)(pa + 4);
    float4 b0 = *(const float4*)pb;
    float4 b1 = *(const float4*)(pb + 4);
    short8 va, vb;
    va[0] = f2bf(a0.x); va[1] = f2bf(a0.y); va[2] = f2bf(a0.z); va[3] = f2bf(a0.w);
    va[4] = f2bf(a1.x); va[5] = f2bf(a1.y); va[6] = f2bf(a1.z); va[7] = f2bf(a1.w);
    vb[0] = f2bf(b0.x); vb[1] = f2bf(b0.y); vb[2] = f2bf(b0.z); vb[3] = f2bf(b0.w);
    vb[4] = f2bf(b1.x); vb[5] = f2bf(b1.y); vb[6] = f2bf(b1.z); vb[7] = f2bf(b1.w);
    wA[kt] = va;
    wB[kt] = vb;
  }

  const ull xroot = (ull)(uintptr_t)xpart + ((ull)(bg * 8 + cp) * 512 + (ull)tid) * 4ull;
  const ull qstep = 4ull * 8 * 512 * 4;  // 65536 B
  const ull xstep = 4ull * qstep;        // 262144 B per t
  const ull hroot = (ull)(uintptr_t)hbuf + (ull)(bg * 16384);
  const ull rdroot = (ull)(uintptr_t)ready;
  unsigned* fbase = flags + bg * 8;

  // prologue gate: tile 0 (t=0,1) must be at the MALL before the first xpart load
  {
    unsigned rv;
    do {
      asm volatile("global_load_dword %0, %1, off sc0 sc1" : "=v"(rv) : "v"(rdroot));
      asm volatile("s_waitcnt vmcnt(0)" ::: "memory");
    } while (!__all((int)(rv >= 16u)));
  }
  unsigned xq0, xq1, xq2, xq3, xn0, xn1, xn2, xn3;
  asm volatile("global_load_dword %0, %1, off" : "=v"(xq0) : "v"(xroot));
  asm volatile("global_load_dword %0, %1, off" : "=v"(xq1) : "v"(xroot + qstep));
  asm volatile("global_load_dword %0, %1, off" : "=v"(xq2) : "v"(xroot + 2 * qstep));
  asm volatile("global_load_dword %0, %1, off" : "=v"(xq3) : "v"(xroot + 3 * qstep));
  asm volatile("s_waitcnt vmcnt(0)" ::: "memory");

  int tile_ok = 0;  // highest tile index confirmed ready (lookahead-4 target)
  float cA = 0.f, cB = 0.f, hAv = 0.f, hBv = 0.f;

  for (int t = 0; t < TT; t++) {
    f32x4 accA = {0.f, 0.f, 0.f, 0.f};
    f32x4 accB = {0.f, 0.f, 0.f, 0.f};
    if (t > 0) {
      // acquire: wave0 polls this bg's 8 flags (one line); others wait at barrier
      if (w == 0) {
        unsigned f;
        do {
          f = __hip_atomic_load(fbase + (lane & 7), __ATOMIC_RELAXED, __HIP_MEMORY_SCOPE_AGENT);
        } while (!__all((int)(f >= (unsigned)t)));
      }
      __syncthreads();
      // dense coherent h loads: this thread stages rows b = p*8+w (p=0,1), 16B at seg=lane
      const ull hb = hroot + (ull)((t & 1) * 65536);
      u32x4 hv[2];
#pragma unroll
      for (int p = 0; p < 2; p++) {
        const ull a = hb + (ull)((p * 8 + w) * 1024 + lane * 16);
        asm volatile("global_load_dwordx4 %0, %1, off sc0 sc1" : "=v"(hv[p]) : "v"(a));
      }
      asm volatile("s_waitcnt vmcnt(0)" ::: "memory");
      __builtin_amdgcn_sched_barrier(0);
      // regs -> LDS (XOR seg-swizzle)
#pragma unroll
      for (int p = 0; p < 2; p++) {
        const int b = p * 8 + w;
        *(u32x4*)(Hs + b * 1024 + ((lane ^ (b & 7)) << 4)) = hv[p];
      }
      __syncthreads();
      // MFMA: B-frag = h[b16][kt*32 + g4*8 ..+8] from swizzled LDS; shared by both chains
#pragma unroll
      for (int kt = 0; kt < 16; kt++) {
        const int sp = ((kt * 4 + g4) ^ (b16 & 7));
        short8 hf = *(const short8*)(Hs + b16 * 1024 + (sp << 4));
        accA = __builtin_amdgcn_mfma_f32_16x16x32_bf16(wA[kt], hf, accA, 0, 0, 0);
        accB = __builtin_amdgcn_mfma_f32_16x16x32_bf16(wB[kt], hf, accB, 0, 0, 0);
      }
    }

    // pointwise: dword q = (cellA gate q | cellB gate q << 16)
    float iA = fsigmoid(accA[0] + h2f((unsigned short)(xq0 & 0xFFFF)));
    float fA = fsigmoid(accA[1] + h2f((unsigned short)(xq1 & 0xFFFF)));
    float gA = ftanh(accA[2] + h2f((unsigned short)(xq2 & 0xFFFF)));
    float oA = fsigmoid(accA[3] + h2f((unsigned short)(xq3 & 0xFFFF)));
    cA = fA * cA + iA * gA;
    hAv = oA * ftanh(cA);
    float iB = fsigmoid(accB[0] + h2f((unsigned short)(xq0 >> 16)));
    float fB = fsigmoid(accB[1] + h2f((unsigned short)(xq1 >> 16)));
    float gB = ftanh(accB[2] + h2f((unsigned short)(xq2 >> 16)));
    float oB = fsigmoid(accB[3] + h2f((unsigned short)(xq3 >> 16)));
    cB = fB * cB + iB * gB;
    hBv = oB * ftanh(cB);

    // release: packed h stores -> drain -> barrier -> flag
    float hAp = __shfl_xor(hAv, 16, 64);
    float hBp = __shfl_xor(hBv, 16, 64);
    if ((g4 & 1) == 0) {
      unsigned* hd = (unsigned*)(hbuf + ((t + 1) & 1) * 65536 + bg * 16384 + b16 * 1024);
      unsigned pkA = (unsigned)(unsigned short)f2bf(hAv) | ((unsigned)(unsigned short)f2bf(hAp) << 16);
      unsigned pkB = (unsigned)(unsigned short)f2bf(hBv) | ((unsigned)(unsigned short)f2bf(hBp) << 16);
      __hip_atomic_store(hd + (colA >> 1), pkA, __ATOMIC_RELAXED, __HIP_MEMORY_SCOPE_AGENT);
      __hip_atomic_store(hd + (colB >> 1), pkB, __ATOMIC_RELAXED, __HIP_MEMORY_SCOPE_AGENT);
    }
    asm volatile("s_waitcnt vmcnt(0)" ::: "memory");
    __syncthreads();
    if (tid == 0)
      __hip_atomic_store(fbase + cp, (unsigned)(t + 1), __ATOMIC_RELAXED, __HIP_MEMORY_SCOPE_AGENT);

    // ready horizon (release shadow): keep tile_ok >= tneed, lookahead 4 tiles
    const int tn = (t + 1 < TT) ? (t + 1) : (TT - 1);
    const int tneed = tn >> 1;
    int ttarget = tneed + 4;
    if (ttarget > 1023) ttarget = 1023;
    while (tile_ok < tneed) {  // ramp only: block until the needed tile exists
      unsigned rv;
      asm volatile("global_load_dword %0, %1, off sc0 sc1"
                   : "=v"(rv) : "v"(rdroot + (ull)(tile_ok + 1) * 4ull));
      asm volatile("s_waitcnt vmcnt(0)" ::: "memory");
      if (__all((int)(rv >= 16u))) tile_ok++;
    }
    if (tile_ok < ttarget) {  // steady state: one opportunistic poll per step
      unsigned rv;
      asm volatile("global_load_dword %0, %1, off sc0 sc1"
                   : "=v"(rv) : "v"(rdroot + (ull)(tile_ok + 1) * 4ull));
      asm volatile("s_waitcnt vmcnt(0)" ::: "memory");
      if (__all((int)(rv >= 16u))) tile_ok++;
    }

    // xpart prefetch (gated): drained by next acquire's vmcnt(0), never hot
    const ull pfb = xroot + (ull)tn * xstep;
    asm volatile("global_load_dword %0, %1, off" : "=v"(xn0) : "v"(pfb));
    asm volatile("global_load_dword %0, %1, off" : "=v"(xn1) : "v"(pfb + qstep));
    asm volatile("global_load_dword %0, %1, off" : "=v"(xn2) : "v"(pfb + 2 * qstep));
    asm volatile("global_load_dword %0, %1, off" : "=v"(xn3) : "v"(pfb + 3 * qstep));

    // outputs drain in the shadow of the next poll
    float* od = outp + ((size_t)t * BB + batchg) * HH;
    od[colA] = hAv;
    od[colB] = hBv;
    xq0 = xn0; xq1 = xn1; xq2 = xn2; xq3 = xn3;
  }

  // final (h_T, c_T)
  float* hT = outp + (size_t)TT * BB * HH;
  float* cT = hT + (size_t)BB * HH;
  hT[(size_t)batchg * HH + colA] = hAv;
  hT[(size_t)batchg * HH + colB] = hBv;
  cT[(size_t)batchg * HH + colA] = cA;
  cT[(size_t)batchg * HH + colB] = cB;
}

__global__ __launch_bounds__(512, 2) void mega_kernel(
    const __hip_bfloat16* __restrict__ Abf, const __hip_bfloat16* __restrict__ Bbf,
    const float* __restrict__ bih, const float* __restrict__ bhh,
    const float* __restrict__ Whh, char* xpart, char* hbuf,
    float* __restrict__ outp, unsigned* sync) {
  __shared__ char smem[32768];
  unsigned* flags = sync;
  unsigned* ready = sync + 64;
  if (blockIdx.x < 32)
    scan_part(smem, xpart, Whh, hbuf, outp, flags, ready);
  else
    gemm_part(smem, blockIdx.x - 32, Abf, Bbf, bih, bhh, xpart, ready);
}

extern "C" void kernel_launch(void* const* d_in, const int* in_sizes, int n_in,
                              void* d_out, int out_size, void* d_ws, size_t ws_size,
                              hipStream_t stream) {
  (void)in_sizes; (void)n_in; (void)out_size; (void)ws_size;
  const float* x = (const float*)d_in[0];
  const float* Wih = (const float*)d_in[1];
  const float* Whh = (const float*)d_in[2];
  const float* bih = (const float*)d_in[3];
  const float* bhh = (const float*)d_in[4];
  float* outp = (float*)d_out;
  char* ws = (char*)d_ws;

  const size_t M = (size_t)TT * BB;  // 131072
  size_t off = 0;
  auto take = [&](size_t sz) { size_t r = off; off = (off + sz + 255) & ~255ULL; return r; };
  const size_t xbf_o = take(M * 512 * 2);
  const size_t wih_o = take((size_t)GG * 512 * 2);
  const size_t hbuf_o = take(2 * 65536);
  const size_t syn_o = take(4608);  // 64 flags + 1024 ready
  const size_t xpart_o = take(M * (size_t)GG * 2);

  __hip_bfloat16* xbf = (__hip_bfloat16*)(ws + xbf_o);
  __hip_bfloat16* wihbf = (__hip_bfloat16*)(ws + wih_o);

  hipMemsetAsync(ws + hbuf_o, 0, 2 * 65536, stream);
  init_sync<<<5, 256, 0, stream>>>((unsigned*)(ws + syn_o));
  cvt_bf16_kernel<<<4096, 256, 0, stream>>>((const float4*)x, (short4v*)xbf, (long)(M * 512 / 4));
  cvt_bf16_kernel<<<256, 256, 0, stream>>>((const float4*)Wih, (short4v*)wihbf, (long)((size_t)GG * 512 / 4));

  mega_kernel<<<32 + 16384, 512, 0, stream>>>(xbf, wihbf, bih, bhh, Whh,
                                              ws + xpart_o, ws + hbuf_o, outp,
                                              (unsigned*)(ws + syn_o));
}

// Round 16
// 7114.535 us; speedup vs baseline: 1.0572x; 1.0572x over previous
//
#include <hip/hip_runtime.h>
#include <hip/hip_bf16.h>
#include <hip/hip_fp16.h>

#define TT 2048
#define BB 64
#define HH 512
#define GG 2048  // 4H

typedef __attribute__((ext_vector_type(4))) float f32x4;
typedef __attribute__((ext_vector_type(8))) short short8;
typedef __attribute__((ext_vector_type(4))) short short4v;
typedef __attribute__((ext_vector_type(4))) unsigned u32x4;
typedef unsigned long long ull;

static __device__ __forceinline__ short f2bf(float f) {
  unsigned u = __builtin_bit_cast(unsigned, f);
  u = (u + 0x7FFFu + ((u >> 16) & 1u)) >> 16;
  return (short)u;
}
static __device__ __forceinline__ float fsigmoid(float x) { return 1.0f / (1.0f + __expf(-x)); }
static __device__ __forceinline__ float ftanh(float x) {
  float e = __expf(2.0f * x);
  return 1.0f - 2.0f / (e + 1.0f);
}
static __device__ __forceinline__ float h2f(unsigned short u) {
  __half h = __builtin_bit_cast(__half, u);
  return __half2float(h);
}

// ---------------- fp32 -> bf16 convert ----------------
__global__ void cvt_bf16_kernel(const float4* __restrict__ in, short4v* __restrict__ outp, long n4) {
  long i = (long)blockIdx.x * blockDim.x + threadIdx.x;
  long stride = (long)gridDim.x * blockDim.x;
  for (; i < n4; i += stride) {
    float4 v = in[i];
    short4v o;
    o[0] = f2bf(v.x); o[1] = f2bf(v.y); o[2] = f2bf(v.z); o[3] = f2bf(v.w);
    outp[i] = o;
  }
}

// ---- sync init: [0..1023] flags (spread, flag i at dword i*16), [1024..2047] ready ----
__global__ void init_sync(unsigned* base) {
  int i = blockIdx.x * 256 + threadIdx.x;
  if (i < 2048)
    __hip_atomic_store(base + i, 0u, __ATOMIC_RELAXED, __HIP_MEMORY_SCOPE_AGENT);
}

// ================= mega-kernel =================
// xpart gate-planar dwords (r10-proven): idx = (((t*4 + q)*4 + bg)*8 + cp)*512 + thr
//   dword = [cellA gate-q f16 | cellB gate-q f16], thr = w*64 + g4*16 + b16 (scan tid)
// ready[mt] counts n-tile blocks (16 each) whose stores for m-tile mt are at the MALL.
// DELTA vs r15: h + flag stores are global_atomic_swap (executed AT the device coherence
// point -> lines MALL-resident -> consumer loads & producer drains MALL-class, not HBM);
// flags spread one-per-64B-line (no producer write contention on a shared line).

// ---- GEMM side: r10's 256-thread gemm_xpart transplanted; threads 256-511 only barrier ----
__device__ __forceinline__ void gemm_part(
    char* smem, int vb,
    const __hip_bfloat16* __restrict__ Abf, const __hip_bfloat16* __restrict__ Bbf,
    const float* __restrict__ bih, const float* __restrict__ bhh,
    char* xpart, unsigned* ready) {
  __hip_bfloat16* As = (__hip_bfloat16*)smem;
  __hip_bfloat16* Bs = As + 8192;
  const int mt = vb >> 4;  // ascending with blockIdx -> tiles complete roughly in t-order
  const int nt = vb & 15;
  const size_t m0 = (size_t)mt * 128;
  const int n0 = nt * 128;
  const int tid = threadIdx.x;
  const int lane = tid & 63;
  const int w = tid >> 6;  // compute uses w 0..3 only
  const int wm = w >> 1, wn = w & 1;
  const int g = lane >> 4;
  const int l15 = lane & 15;
  f32x4 acc[4][4] = {};
  for (int k0 = 0; k0 < 512; k0 += 64) {
    if (tid < 256) {
#pragma unroll
      for (int i = 0; i < 4; i++) {
        const int slot = w * 4 + i;
        const int row = slot * 8 + (lane >> 3);
        const int segS = (lane & 7) ^ (row & 7);
        const __hip_bfloat16* ga = Abf + (m0 + row) * 512 + k0 + segS * 8;
        const __hip_bfloat16* gb = Bbf + (size_t)(n0 + row) * 512 + k0 + segS * 8;
        __builtin_amdgcn_global_load_lds(
            (const __attribute__((address_space(1))) unsigned*)(const void*)ga,
            (__attribute__((address_space(3))) unsigned*)(void*)(As + slot * 512), 16, 0, 0);
        __builtin_amdgcn_global_load_lds(
            (const __attribute__((address_space(1))) unsigned*)(const void*)gb,
            (__attribute__((address_space(3))) unsigned*)(void*)(Bs + slot * 512), 16, 0, 0);
      }
    }
    __syncthreads();
    if (tid < 256) {
#pragma unroll
      for (int kk = 0; kk < 2; kk++) {
        short8 av[4], bv[4];
#pragma unroll
        for (int f = 0; f < 4; f++) {
          const int row = wm * 64 + f * 16 + l15;
          av[f] = *(const short8*)(As + row * 64 + ((((kk << 2) + g) ^ (row & 7)) << 3));
        }
#pragma unroll
        for (int f = 0; f < 4; f++) {
          const int row = wn * 64 + f * 16 + l15;
          bv[f] = *(const short8*)(Bs + row * 64 + ((((kk << 2) + g) ^ (row & 7)) << 3));
        }
#pragma unroll
        for (int fi = 0; fi < 4; fi++)
#pragma unroll
          for (int fj = 0; fj < 4; fj++)
            acc[fi][fj] = __builtin_amdgcn_mfma_f32_16x16x32_bf16(av[fi], bv[fj], acc[fi][fj], 0, 0, 0);
      }
    }
    __syncthreads();
  }
  // epilogue: r10 address math; fj and fj+2 share one dword (slot 0/1) -> packed sc0sc1 store
  if (tid < 256) {
    const int q = nt >> 2;
    const int gt = mt * 2 + wm;
    const int cp = (nt & 3) * 2 + wn;
    const int g4s = l15 & 3;
#pragma unroll
    for (int fjp = 0; fjp < 2; fjp++) {
      const int nlo = n0 + wn * 64 + fjp * 16 + l15;
      const int nhi = nlo + 32;
      const float bLo = bih[nlo] + bhh[nlo];
      const float bHi = bih[nhi] + bhh[nhi];
      const int wpart = fjp * 4 + (l15 >> 2);
#pragma unroll
      for (int fi = 0; fi < 4; fi++) {
#pragma unroll
        for (int r = 0; r < 4; r++) {
          const int thr = wpart * 64 + g4s * 16 + (g * 4 + r);
          __half lo = __float2half(acc[fi][fjp][r] + bLo);
          __half hi = __float2half(acc[fi][fjp + 2][r] + bHi);
          unsigned d = (unsigned)__builtin_bit_cast(unsigned short, lo) |
                       ((unsigned)__builtin_bit_cast(unsigned short, hi) << 16);
          const ull dwi = ((((ull)gt * 4 + q) * 4 + fi) * 8 + cp) * 512 + (ull)thr;
          const ull ga = (ull)(uintptr_t)xpart + dwi * 4ull;
          asm volatile("global_store_dword %0, %1, off sc0 sc1" ::"v"(ga), "v"(d));
        }
      }
    }
    asm volatile("s_waitcnt vmcnt(0)" ::: "memory");
  }
  __syncthreads();
  if (tid == 0)
    __hip_atomic_fetch_add(ready + mt, 1u, __ATOMIC_RELAXED, __HIP_MEMORY_SCOPE_AGENT);
}

// ---- scan side: r15 verbatim except atomic-swap h/flag stores + spread flags ----
__device__ __forceinline__ void scan_part(
    char* smem, const char* xpart, const float* __restrict__ Whh,
    char* hbuf, float* __restrict__ outp, unsigned* flags, unsigned* ready) {
  char* Hs = smem;  // 16KB: [b(16)][seg(64) x 16B], seg stored at (seg ^ (b&7))
  const int blk = blockIdx.x;
  const int bg = blk >> 3;
  const int cp = blk & 7;
  const int tid = threadIdx.x;
  const int lane = tid & 63;
  const int w = tid >> 6;  // 0..7
  const int b16 = lane & 15;
  const int g4 = lane >> 4;
  const int qr = b16 & 3;
  const int jj = b16 >> 2;
  const int colA = cp * 64 + w * 4 + g4;
  const int colB = cp * 64 + (w + 8) * 4 + g4;
  const int batchg = bg * 16 + b16;

  // one-time: W_hh slices -> registers (bf16 A-frags)
  const int rowA = qr * 512 + cp * 64 + w * 4 + jj;
  const int rowB = qr * 512 + cp * 64 + (w + 8) * 4 + jj;
  short8 wA[16], wB[16];
#pragma unroll
  for (int kt = 0; kt < 16; kt++) {
    const float* pa = Whh + (size_t)rowA * 512 + kt * 32 + g4 * 8;
    const float* pb = Whh + (size_t)rowB * 512 + kt * 32 + g4 * 8;
    float4 a0 = *(const float4*)pa;
    float4 a1 = *(const float4*)(pa + 4);
    float4 b0 = *(const float4*)pb;
    float4 b1 = *(const float4*)(pb + 4);
    short8 va, vb;
    va[0] = f2bf(a0.x); va[1] = f2bf(a0.y); va[2] = f2bf(a0.z); va[3] = f2bf(a0.w);
    va[4] = f2bf(a1.x); va[5] = f2bf(a1.y); va[6] = f2bf(a1.z); va[7] = f2bf(a1.w);
    vb[0] = f2bf(b0.x); vb[1] = f2bf(b0.y); vb[2] = f2bf(b0.z); vb[3] = f2bf(b0.w);
    vb[4] = f2bf(b1.x); vb[5] = f2bf(b1.y); vb[6] = f2bf(b1.z); vb[7] = f2bf(b1.w);
    wA[kt] = va;
    wB[kt] = vb;
  }

  const ull xroot = (ull)(uintptr_t)xpart + ((ull)(bg * 8 + cp) * 512 + (ull)tid) * 4ull;
  const ull qstep = 4ull * 8 * 512 * 4;  // 65536 B
  const ull xstep = 4ull * qstep;        // 262144 B per t
  const ull hroot = (ull)(uintptr_t)hbuf + (ull)(bg * 16384);
  const ull rdroot = (ull)(uintptr_t)ready;
  // spread flags: flag (bg,cp) lives at dword (bg*8+cp)*16  (one 64B line each)
  unsigned* fbase = flags + bg * 8 * 16;

  // prologue gate: tile 0 (t=0,1) must be at the MALL before the first xpart load
  {
    unsigned rv;
    do {
      asm volatile("global_load_dword %0, %1, off sc0 sc1" : "=v"(rv) : "v"(rdroot));
      asm volatile("s_waitcnt vmcnt(0)" ::: "memory");
    } while (!__all((int)(rv >= 16u)));
  }
  unsigned xq0, xq1, xq2, xq3, xn0, xn1, xn2, xn3;
  asm volatile("global_load_dword %0, %1, off" : "=v"(xq0) : "v"(xroot));
  asm volatile("global_load_dword %0, %1, off" : "=v"(xq1) : "v"(xroot + qstep));
  asm volatile("global_load_dword %0, %1, off" : "=v"(xq2) : "v"(xroot + 2 * qstep));
  asm volatile("global_load_dword %0, %1, off" : "=v"(xq3) : "v"(xroot + 3 * qstep));
  asm volatile("s_waitcnt vmcnt(0)" ::: "memory");

  int tile_ok = 0;  // highest tile index confirmed ready (lookahead-4 target)
  float cA = 0.f, cB = 0.f, hAv = 0.f, hBv = 0.f;

  for (int t = 0; t < TT; t++) {
    f32x4 accA = {0.f, 0.f, 0.f, 0.f};
    f32x4 accB = {0.f, 0.f, 0.f, 0.f};
    if (t > 0) {
      // acquire: wave0 polls this bg's 8 flags (8 distinct lines, 1 load each); barrier
      if (w == 0) {
        const ull fla = (ull)(uintptr_t)(fbase + (lane & 7) * 16);
        unsigned fv;
        do {
          asm volatile("global_load_dword %0, %1, off sc0 sc1" : "=v"(fv) : "v"(fla));
          asm volatile("s_waitcnt vmcnt(0)" ::: "memory");
          __builtin_amdgcn_sched_barrier(0);
        } while (!__all((int)(fv >= (unsigned)t)));
      }
      __syncthreads();
      // dense coherent h loads: this thread stages rows b = p*8+w (p=0,1), 16B at seg=lane
      const ull hb = hroot + (ull)((t & 1) * 65536);
      u32x4 hv[2];
#pragma unroll
      for (int p = 0; p < 2; p++) {
        const ull a = hb + (ull)((p * 8 + w) * 1024 + lane * 16);
        asm volatile("global_load_dwordx4 %0, %1, off sc0 sc1" : "=v"(hv[p]) : "v"(a));
      }
      asm volatile("s_waitcnt vmcnt(0)" ::: "memory");
      __builtin_amdgcn_sched_barrier(0);
      // regs -> LDS (XOR seg-swizzle)
#pragma unroll
      for (int p = 0; p < 2; p++) {
        const int b = p * 8 + w;
        *(u32x4*)(Hs + b * 1024 + ((lane ^ (b & 7)) << 4)) = hv[p];
      }
      __syncthreads();
      // MFMA: B-frag = h[b16][kt*32 + g4*8 ..+8] from swizzled LDS; shared by both chains
#pragma unroll
      for (int kt = 0; kt < 16; kt++) {
        const int sp = ((kt * 4 + g4) ^ (b16 & 7));
        short8 hf = *(const short8*)(Hs + b16 * 1024 + (sp << 4));
        accA = __builtin_amdgcn_mfma_f32_16x16x32_bf16(wA[kt], hf, accA, 0, 0, 0);
        accB = __builtin_amdgcn_mfma_f32_16x16x32_bf16(wB[kt], hf, accB, 0, 0, 0);
      }
    }

    // pointwise: dword q = (cellA gate q | cellB gate q << 16)
    float iA = fsigmoid(accA[0] + h2f((unsigned short)(xq0 & 0xFFFF)));
    float fA = fsigmoid(accA[1] + h2f((unsigned short)(xq1 & 0xFFFF)));
    float gA = ftanh(accA[2] + h2f((unsigned short)(xq2 & 0xFFFF)));
    float oA = fsigmoid(accA[3] + h2f((unsigned short)(xq3 & 0xFFFF)));
    cA = fA * cA + iA * gA;
    hAv = oA * ftanh(cA);
    float iB = fsigmoid(accB[0] + h2f((unsigned short)(xq0 >> 16)));
    float fB = fsigmoid(accB[1] + h2f((unsigned short)(xq1 >> 16)));
    float gB = ftanh(accB[2] + h2f((unsigned short)(xq2 >> 16)));
    float oB = fsigmoid(accB[3] + h2f((unsigned short)(xq3 >> 16)));
    cB = fB * cB + iB * gB;
    hBv = oB * ftanh(cB);

    // release: packed h ATOMIC-SWAP stores (execute at the MALL -> line resident there)
    float hAp = __shfl_xor(hAv, 16, 64);
    float hBp = __shfl_xor(hBv, 16, 64);
    if ((g4 & 1) == 0) {
      const ull hd = (ull)(uintptr_t)hbuf +
                     (ull)(((t + 1) & 1) * 65536 + bg * 16384 + b16 * 1024);
      unsigned pkA = (unsigned)(unsigned short)f2bf(hAv) | ((unsigned)(unsigned short)f2bf(hAp) << 16);
      unsigned pkB = (unsigned)(unsigned short)f2bf(hBv) | ((unsigned)(unsigned short)f2bf(hBp) << 16);
      const ull aA = hd + (ull)((colA >> 1) * 4);
      const ull aB = hd + (ull)((colB >> 1) * 4);
      asm volatile("global_atomic_swap %0, %1, off" ::"v"(aA), "v"(pkA));
      asm volatile("global_atomic_swap %0, %1, off" ::"v"(aB), "v"(pkB));
    }
    asm volatile("s_waitcnt vmcnt(0)" ::: "memory");
    __syncthreads();
    if (tid == 0) {
      const ull fla = (ull)(uintptr_t)(fbase + cp * 16);
      unsigned tv = (unsigned)(t + 1);
      asm volatile("global_atomic_swap %0, %1, off" ::"v"(fla), "v"(tv));
    }

    // ready horizon (release shadow): keep tile_ok >= tneed, lookahead 4 tiles
    const int tn = (t + 1 < TT) ? (t + 1) : (TT - 1);
    const int tneed = tn >> 1;
    int ttarget = tneed + 4;
    if (ttarget > 1023) ttarget = 1023;
    while (tile_ok < tneed) {  // ramp only: block until the needed tile exists
      unsigned rv;
      asm volatile("global_load_dword %0, %1, off sc0 sc1"
                   : "=v"(rv) : "v"(rdroot + (ull)(tile_ok + 1) * 4ull));
      asm volatile("s_waitcnt vmcnt(0)" ::: "memory");
      if (__all((int)(rv >= 16u))) tile_ok++;
    }
    if (tile_ok < ttarget) {  // steady state: one opportunistic poll per step
      unsigned rv;
      asm volatile("global_load_dword %0, %1, off sc0 sc1"
                   : "=v"(rv) : "v"(rdroot + (ull)(tile_ok + 1) * 4ull));
      asm volatile("s_waitcnt vmcnt(0)" ::: "memory");
      if (__all((int)(rv >= 16u))) tile_ok++;
    }

    // xpart prefetch (gated): drained by next acquire's vmcnt(0), never hot
    const ull pfb = xroot + (ull)tn * xstep;
    asm volatile("global_load_dword %0, %1, off" : "=v"(xn0) : "v"(pfb));
    asm volatile("global_load_dword %0, %1, off" : "=v"(xn1) : "v"(pfb + qstep));
    asm volatile("global_load_dword %0, %1, off" : "=v"(xn2) : "v"(pfb + 2 * qstep));
    asm volatile("global_load_dword %0, %1, off" : "=v"(xn3) : "v"(pfb + 3 * qstep));

    // outputs drain in the shadow of the next poll
    float* od = outp + ((size_t)t * BB + batchg) * HH;
    od[colA] = hAv;
    od[colB] = hBv;
    xq0 = xn0; xq1 = xn1; xq2 = xn2; xq3 = xn3;
  }

  // final (h_T, c_T)
  float* hT = outp + (size_t)TT * BB * HH;
  float* cT = hT + (size_t)BB * HH;
  hT[(size_t)batchg * HH + colA] = hAv;
  hT[(size_t)batchg * HH + colB] = hBv;
  cT[(size_t)batchg * HH + colA] = cA;
  cT[(size_t)batchg * HH + colB] = cB;
}

__global__ __launch_bounds__(512, 2) void mega_kernel(
    const __hip_bfloat16* __restrict__ Abf, const __hip_bfloat16* __restrict__ Bbf,
    const float* __restrict__ bih, const float* __restrict__ bhh,
    const float* __restrict__ Whh, char* xpart, char* hbuf,
    float* __restrict__ outp, unsigned* sync) {
  __shared__ char smem[32768];
  unsigned* flags = sync;          // 1024 dwords (64 flags spread 1-per-line)
  unsigned* ready = sync + 1024;   // 1024 dwords
  if (blockIdx.x < 32)
    scan_part(smem, xpart, Whh, hbuf, outp, flags, ready);
  else
    gemm_part(smem, blockIdx.x - 32, Abf, Bbf, bih, bhh, xpart, ready);
}

extern "C" void kernel_launch(void* const* d_in, const int* in_sizes, int n_in,
                              void* d_out, int out_size, void* d_ws, size_t ws_size,
                              hipStream_t stream) {
  (void)in_sizes; (void)n_in; (void)out_size; (void)ws_size;
  const float* x = (const float*)d_in[0];
  const float* Wih = (const float*)d_in[1];
  const float* Whh = (const float*)d_in[2];
  const float* bih = (const float*)d_in[3];
  const float* bhh = (const float*)d_in[4];
  float* outp = (float*)d_out;
  char* ws = (char*)d_ws;

  const size_t M = (size_t)TT * BB;  // 131072
  size_t off = 0;
  auto take = [&](size_t sz) { size_t r = off; off = (off + sz + 255) & ~255ULL; return r; };
  const size_t xbf_o = take(M * 512 * 2);
  const size_t wih_o = take((size_t)GG * 512 * 2);
  const size_t hbuf_o = take(2 * 65536);
  const size_t syn_o = take(8192);  // 1024 spread flags + 1024 ready
  const size_t xpart_o = take(M * (size_t)GG * 2);

  __hip_bfloat16* xbf = (__hip_bfloat16*)(ws + xbf_o);
  __hip_bfloat16* wihbf = (__hip_bfloat16*)(ws + wih_o);

  hipMemsetAsync(ws + hbuf_o, 0, 2 * 65536, stream);
  init_sync<<<8, 256, 0, stream>>>((unsigned*)(ws + syn_o));
  cvt_bf16_kernel<<<4096, 256, 0, stream>>>((const float4*)x, (short4v*)xbf, (long)(M * 512 / 4));
  cvt_bf16_kernel<<<256, 256, 0, stream>>>((const float4*)Wih, (short4v*)wihbf, (long)((size_t)GG * 512 / 4));

  mega_kernel<<<32 + 16384, 512, 0, stream>>>(xbf, wihbf, bih, bhh, Whh,
                                              ws + xpart_o, ws + hbuf_o, outp,
                                              (unsigned*)(ws + syn_o));
}